// Round 5
// baseline (159.231 us; speedup 1.0000x reference)
//
#include <hip/hip_runtime.h>
#include <utility>

#define D_DIM 256
#define WID   33
#define CEN   16
#define RSTR  64                   // rows per block (one strip, fully unrolled)
#define WINW  (RSTR + WID - 1)     // 96-row register window, streamed

// Every index below is a template/fold constant -> constant GEPs at IR-gen
// time. The compiler streams loads into the FMA chains (round-4 behavior),
// so liveness stays low; issued x-traffic = WINW/RSTR = 1.5x (was 5x).

template <size_t... Is>
__device__ __forceinline__ void load_win(float (&W)[WINW],
                                         const float* __restrict__ xb,
                                         int n0, int N,
                                         std::index_sequence<Is...>) {
    // pos is wave-uniform -> scalar compare/branch, no divergence
    ((W[Is] = ((n0 - CEN + (int)Is) >= 0 && (n0 - CEN + (int)Is) < N)
                  ? xb[(size_t)(n0 - CEN + (int)Is) * D_DIM]
                  : 0.0f),
     ...);
}

template <int Rr, size_t... Is>
__device__ __forceinline__ float dot_row(const float (&W)[WINW],
                                         const float* __restrict__ wrow,
                                         std::index_sequence<Is...>) {
    float acc[4] = {0.f, 0.f, 0.f, 0.f};
    ((acc[Is & 3] = fmaf(W[Rr + (int)Is], wrow[Is], acc[Is & 3])), ...);
    return (acc[0] + acc[1]) + (acc[2] + acc[3]);
}

template <size_t... Rs>
__device__ __forceinline__ void all_rows(const float (&W)[WINW],
                                         const float* __restrict__ smb,
                                         const float* __restrict__ szb,
                                         float* __restrict__ ob,
                                         int n0, std::index_sequence<Rs...>) {
    (([&] {
         const int n = n0 + (int)Rs;
         const float* __restrict__ wrow = smb + (size_t)n * WID;  // wave-uniform
         const float s = dot_row<(int)Rs>(W, wrow, std::make_index_sequence<WID>{});
         const float inv = 1.0f / fmaxf(szb[n], 1e-6f);
         ob[(size_t)n * D_DIM] = s * inv;
     }()),
     ...);
}

__global__ __launch_bounds__(256) void local_enc_kernel(
    const float* __restrict__ x, const float* __restrict__ sizev,
    const float* __restrict__ sm, float* __restrict__ out, int N) {
    // XCD-aware swizzle: 2048 blocks, XCD k (= bid%8) gets swz in
    // [k*256, (k+1)*256) = one full batch, n-strips in consecutive order
    // -> the 32-row halo between adjacent strips hits that XCD's L2.
    const int bid   = blockIdx.x;
    const int swz   = (bid & 7) * 256 + (bid >> 3);
    const int strip = swz & 255;
    const int b     = swz >> 8;
    const int n0    = strip * RSTR;
    const int d     = threadIdx.x;

    const size_t bN = (size_t)b * (size_t)N;
    const float* __restrict__ xb  = x   + bN * D_DIM + d;
    float*       __restrict__ ob  = out + bN * D_DIM + d;
    const float* __restrict__ smb = sm    + bN * WID;   // wave-uniform
    const float* __restrict__ szb = sizev + bN;         // wave-uniform

    float W[WINW];
    load_win(W, xb, n0, N, std::make_index_sequence<WINW>{});
    all_rows(W, smb, szb, ob, n0, std::make_index_sequence<RSTR>{});
}

extern "C" void kernel_launch(void* const* d_in, const int* in_sizes, int n_in,
                              void* d_out, int out_size, void* d_ws, size_t ws_size,
                              hipStream_t stream) {
    const float* x  = (const float*)d_in[0];
    const float* sz = (const float*)d_in[1];
    const float* sm = (const float*)d_in[2];
    float* out = (float*)d_out;

    const int B = 8;
    const int N = 16384;

    dim3 grid((N / RSTR) * B, 1, 1);   // 256 strips * 8 batches = 2048
    dim3 block(D_DIM, 1, 1);
    local_enc_kernel<<<grid, block, 0, stream>>>(x, sz, sm, out, N);
}

// Round 6
// 123.568 us; speedup vs baseline: 1.2886x; 1.2886x over previous
//
#include <hip/hip_runtime.h>
#include <utility>

#define D_DIM 256
#define WID   33
#define CEN   16
#define CHUNK 66            // 2 * WID — phase pattern repeats every 33 rows

// Ring-buffer sliding window, all indices template constants:
//  - rounds 1-3 proved rolled loops leave dynamic GEPs -> scratch (VGPR=28)
//  - round 4 proved fold-exprs with literal indices -> SROA promotes to VGPRs
//  - round 5 proved a 96-wide streamed window -> waitcnt serialization
// This combines: 33 live values (fits VGPR budget), 1 load+33 FMA+1 store per
// row, load issued BEFORE the dot and committed after (latency hidden).

template <int JJ, size_t... Is>
__device__ __forceinline__ float dot_ring(const float (&W)[WID],
                                          const float* __restrict__ wrow,
                                          std::index_sequence<Is...>) {
    float acc[4] = {0.f, 0.f, 0.f, 0.f};
    ((acc[Is & 3] = fmaf(W[(JJ + (int)Is) % WID], wrow[Is], acc[Is & 3])), ...);
    return (acc[0] + acc[1]) + (acc[2] + acc[3]);
}

template <int JJ>
__device__ __forceinline__ void row_step(float (&W)[WID],
                                         const float* __restrict__ xb,
                                         const float* __restrict__ smb,
                                         const float* __restrict__ szb,
                                         float* __restrict__ ob,
                                         int nbase, int N) {
    const int n = nbase + JJ;

    // issue next x load EARLY (independent of the dot) -> hides under FMAs
    const int pos = n + CEN + 1;                       // always >= 17
    const float xn = (pos < N) ? xb[(size_t)pos * D_DIM] : 0.0f;

    if (n < N) {                                       // wave-uniform guard
        const float* __restrict__ wrow = smb + (size_t)n * WID;  // uniform -> s_load
        const float s = dot_ring<JJ>(W, wrow, std::make_index_sequence<WID>{});
        const float inv = 1.0f / fmaxf(szb[n], 1e-6f);
        ob[(size_t)n * D_DIM] = s * inv;
    }

    W[JJ] = xn;   // constant index -> stays in VGPR
}

template <size_t... JJs>
__device__ __forceinline__ void phase_block(float (&W)[WID],
                                            const float* __restrict__ xb,
                                            const float* __restrict__ smb,
                                            const float* __restrict__ szb,
                                            float* __restrict__ ob,
                                            int nbase, int N,
                                            std::index_sequence<JJs...>) {
    (row_step<(int)JJs>(W, xb, smb, szb, ob, nbase, N), ...);
}

__global__ __launch_bounds__(256) void local_enc_kernel(
    const float* __restrict__ x, const float* __restrict__ sizev,
    const float* __restrict__ sm, float* __restrict__ out, int N) {
    const int d  = threadIdx.x;
    const int b  = blockIdx.y;
    const int n0 = blockIdx.x * CHUNK;

    const size_t bN = (size_t)b * (size_t)N;
    const float* __restrict__ xb  = x   + bN * D_DIM + d;
    float*       __restrict__ ob  = out + bN * D_DIM + d;
    const float* __restrict__ smb = sm    + bN * WID;   // wave-uniform
    const float* __restrict__ szb = sizev + bN;         // wave-uniform

    // init: W[i] = x[b, n0 - CEN + i, d], phase invariant for JJ=0:
    //   W[(0 + i) % WID] == x[n0 - CEN + i]
    float W[WID];
#pragma unroll
    for (int i = 0; i < WID; ++i) {
        const int pos = n0 - CEN + i;                  // uniform guard
        W[i] = (pos >= 0 && pos < N) ? xb[(size_t)pos * D_DIM] : 0.0f;
    }

#pragma unroll 1
    for (int m = 0; m < CHUNK / WID; ++m) {
        phase_block(W, xb, smb, szb, ob, n0 + m * WID, N,
                    std::make_index_sequence<WID>{});
    }
}

extern "C" void kernel_launch(void* const* d_in, const int* in_sizes, int n_in,
                              void* d_out, int out_size, void* d_ws, size_t ws_size,
                              hipStream_t stream) {
    const float* x  = (const float*)d_in[0];
    const float* sz = (const float*)d_in[1];
    const float* sm = (const float*)d_in[2];
    float* out = (float*)d_out;

    const int B = 8;
    const int N = 16384;

    dim3 grid((N + CHUNK - 1) / CHUNK, B, 1);   // 249 x 8 = 1992 blocks
    dim3 block(D_DIM, 1, 1);
    local_enc_kernel<<<grid, block, 0, stream>>>(x, sz, sm, out, N);
}

// Round 7
// 123.468 us; speedup vs baseline: 1.2897x; 1.0008x over previous
//
#include <hip/hip_runtime.h>
#include <utility>

#define D_DIM 256
#define WID   33
#define CEN   16
#define CHUNK 66            // 2 * WID — phase pattern repeats every 33 rows

// Ring-buffer sliding window. EVERY access to W[] — including the init —
// is a fold-expression with a literal index, so every GEP is constant at
// IR-gen time and SROA promotes the array to 33 SSA floats (VGPRs).
// Round-6 failure mode: the rolled init loop (dynamic GEP at SROA time)
// blocked promotion of the WHOLE array -> scratch -> 124 us plateau.

template <size_t... Is>
__device__ __forceinline__ void init_win(float (&W)[WID],
                                         const float* __restrict__ xb,
                                         int n0, int N,
                                         std::index_sequence<Is...>) {
    ((W[Is] = ((n0 - CEN + (int)Is) >= 0 && (n0 - CEN + (int)Is) < N)
                  ? xb[(size_t)(n0 - CEN + (int)Is) * D_DIM]
                  : 0.0f),
     ...);
}

template <int JJ, size_t... Is>
__device__ __forceinline__ float dot_ring(const float (&W)[WID],
                                          const float* __restrict__ wrow,
                                          std::index_sequence<Is...>) {
    float acc[4] = {0.f, 0.f, 0.f, 0.f};
    ((acc[Is & 3] = fmaf(W[(JJ + (int)Is) % WID], wrow[Is], acc[Is & 3])), ...);
    return (acc[0] + acc[1]) + (acc[2] + acc[3]);
}

template <int JJ>
__device__ __forceinline__ void row_step(float (&W)[WID],
                                         const float* __restrict__ xb,
                                         const float* __restrict__ smb,
                                         const float* __restrict__ szb,
                                         float* __restrict__ ob,
                                         int nbase, int N) {
    const int n = nbase + JJ;

    // issue the incoming x row EARLY (independent of the dot) -> latency
    // hides under the 33 FMAs; committed to W[JJ] after the dot.
    const int pos = n + CEN + 1;                       // always >= 17
    const float xn = (pos < N) ? xb[(size_t)pos * D_DIM] : 0.0f;

    if (n < N) {                                       // wave-uniform guard
        const float* __restrict__ wrow = smb + (size_t)n * WID;  // uniform -> s_load
        const float s = dot_ring<JJ>(W, wrow, std::make_index_sequence<WID>{});
        const float inv = 1.0f / fmaxf(szb[n], 1e-6f);
        ob[(size_t)n * D_DIM] = s * inv;
    }

    W[JJ] = xn;   // literal index -> VGPR
}

template <size_t... JJs>
__device__ __forceinline__ void phase_block(float (&W)[WID],
                                            const float* __restrict__ xb,
                                            const float* __restrict__ smb,
                                            const float* __restrict__ szb,
                                            float* __restrict__ ob,
                                            int nbase, int N,
                                            std::index_sequence<JJs...>) {
    (row_step<(int)JJs>(W, xb, smb, szb, ob, nbase, N), ...);
}

__global__ __launch_bounds__(256) void local_enc_kernel(
    const float* __restrict__ x, const float* __restrict__ sizev,
    const float* __restrict__ sm, float* __restrict__ out, int N) {
    const int d  = threadIdx.x;
    const int b  = blockIdx.y;
    const int n0 = blockIdx.x * CHUNK;

    const size_t bN = (size_t)b * (size_t)N;
    const float* __restrict__ xb  = x   + bN * D_DIM + d;
    float*       __restrict__ ob  = out + bN * D_DIM + d;
    const float* __restrict__ smb = sm    + bN * WID;   // wave-uniform
    const float* __restrict__ szb = sizev + bN;         // wave-uniform

    float W[WID];
    init_win(W, xb, n0, N, std::make_index_sequence<WID>{});

#pragma unroll 1
    for (int m = 0; m < CHUNK / WID; ++m) {
        phase_block(W, xb, smb, szb, ob, n0 + m * WID, N,
                    std::make_index_sequence<WID>{});
    }
}

extern "C" void kernel_launch(void* const* d_in, const int* in_sizes, int n_in,
                              void* d_out, int out_size, void* d_ws, size_t ws_size,
                              hipStream_t stream) {
    const float* x  = (const float*)d_in[0];
    const float* sz = (const float*)d_in[1];
    const float* sm = (const float*)d_in[2];
    float* out = (float*)d_out;

    const int B = 8;
    const int N = 16384;

    dim3 grid((N + CHUNK - 1) / CHUNK, B, 1);   // 249 x 8 = 1992 blocks
    dim3 block(D_DIM, 1, 1);
    local_enc_kernel<<<grid, block, 0, stream>>>(x, sz, sm, out, N);
}

// Round 8
// 111.367 us; speedup vs baseline: 1.4298x; 1.1087x over previous
//
#include <hip/hip_runtime.h>
#include <utility>

#define D_DIM 256
#define WID   33
#define CEN   16
#define RSTR  33                   // rows per block — ONE strip, zero loops
#define WINW  (RSTR + WID - 1)     // 65-value window

// Lessons from R1-R7: SROA promotes W[] only when (a) every GEP index is a
// front-end constant (fold expressions) AND (b) the array does NOT cross a
// loop back-edge (R4/R5 promoted; R1-3/6-7 loop-carried -> scratch, VGPR~28,
// ~125us plateau). This kernel is fully straight-line: 65 loads, 33 dots.
// Row r reads W[r..r+32] -> any schedule keeps >=33 values live; issued
// x-traffic is 65/33 = 1.97x, halo absorbed by L2/L3.

template <size_t... Is>
__device__ __forceinline__ void load_win(float (&W)[WINW],
                                         const float* __restrict__ xb,
                                         int base, std::index_sequence<Is...>) {
    ((W[Is] = xb[(size_t)(base + (int)Is) * D_DIM]), ...);
}

template <size_t... Is>
__device__ __forceinline__ void load_win_guard(float (&W)[WINW],
                                               const float* __restrict__ xb,
                                               int base, int N,
                                               std::index_sequence<Is...>) {
    ((W[Is] = (base + (int)Is >= 0 && base + (int)Is < N)
                  ? xb[(size_t)(base + (int)Is) * D_DIM]
                  : 0.0f),
     ...);
}

template <int Rr, size_t... Is>
__device__ __forceinline__ float dot_row(const float (&W)[WINW],
                                         const float* __restrict__ wrow,
                                         std::index_sequence<Is...>) {
    float acc[4] = {0.f, 0.f, 0.f, 0.f};
    ((acc[Is & 3] = fmaf(W[Rr + (int)Is], wrow[Is], acc[Is & 3])), ...);
    return (acc[0] + acc[1]) + (acc[2] + acc[3]);
}

template <size_t... Rs>
__device__ __forceinline__ void all_rows(const float (&W)[WINW],
                                         const float* __restrict__ smb,
                                         const float* __restrict__ szb,
                                         float* __restrict__ ob,
                                         int n0, int N, bool full,
                                         std::index_sequence<Rs...>) {
    (([&] {
         const int n = n0 + (int)Rs;
         if (full || n < N) {                            // wave-uniform
             const float* __restrict__ wrow = smb + (size_t)n * WID; // s_load
             const float s =
                 dot_row<(int)Rs>(W, wrow, std::make_index_sequence<WID>{});
             const float inv = __builtin_amdgcn_rcpf(fmaxf(szb[n], 1e-6f));
             ob[(size_t)n * D_DIM] = s * inv;
         }
     }()),
     ...);
}

__global__ __launch_bounds__(256, 4) void local_enc_kernel(
    const float* __restrict__ x, const float* __restrict__ sizev,
    const float* __restrict__ sm, float* __restrict__ out, int N) {
    const int d  = threadIdx.x;
    const int b  = blockIdx.y;
    const int n0 = blockIdx.x * RSTR;

    const size_t bN = (size_t)b * (size_t)N;
    const float* __restrict__ xb  = x   + bN * D_DIM + d;
    float*       __restrict__ ob  = out + bN * D_DIM + d;
    const float* __restrict__ smb = sm    + bN * WID;   // wave-uniform
    const float* __restrict__ szb = sizev + bN;         // wave-uniform

    const int  base     = n0 - CEN;                      // first window row
    const bool interior = (base >= 0) && (base + WINW <= N);
    const bool full     = (n0 + RSTR <= N);

    float W[WINW];
    if (interior)
        load_win(W, xb, base, std::make_index_sequence<WINW>{});
    else
        load_win_guard(W, xb, base, N, std::make_index_sequence<WINW>{});

    all_rows(W, smb, szb, ob, n0, N, full, std::make_index_sequence<RSTR>{});
}

extern "C" void kernel_launch(void* const* d_in, const int* in_sizes, int n_in,
                              void* d_out, int out_size, void* d_ws, size_t ws_size,
                              hipStream_t stream) {
    const float* x  = (const float*)d_in[0];
    const float* sz = (const float*)d_in[1];
    const float* sm = (const float*)d_in[2];
    float* out = (float*)d_out;

    const int B = 8;
    const int N = 16384;

    dim3 grid((N + RSTR - 1) / RSTR, B, 1);   // 497 x 8 = 3976 blocks
    dim3 block(D_DIM, 1, 1);
    local_enc_kernel<<<grid, block, 0, stream>>>(x, sz, sm, out, N);
}

// Round 9
// 110.859 us; speedup vs baseline: 1.4363x; 1.0046x over previous
//
#include <hip/hip_runtime.h>
#include <utility>

#define D_DIM 256
#define WID   33
#define CEN   16
#define RSTR  33                   // rows per block — ONE strip, zero loops
#define WINW  (RSTR + WID - 1)     // 65-value window

// R8 post-mortem: straight-line strip worked (no scratch, fetch ~1.13x
// unique) but backend SANK loads into the FMA stream (VGPR=40 < 65) ->
// each wave pays x-load latency ~10x with only ~5 waves/SIMD to cover it.
// Fix: a memory-clobber asm fence between the 65 loads and the 33 dots.
// Loads are memory ops -> cannot cross the fence -> all 65 issued
// back-to-back, ONE vmcnt drain per wave, values pinned live in VGPRs.

template <size_t... Is>
__device__ __forceinline__ void load_win(float (&W)[WINW],
                                         const float* __restrict__ xb,
                                         int base, std::index_sequence<Is...>) {
    ((W[Is] = xb[(size_t)(base + (int)Is) * D_DIM]), ...);
}

template <size_t... Is>
__device__ __forceinline__ void load_win_guard(float (&W)[WINW],
                                               const float* __restrict__ xb,
                                               int base, int N,
                                               std::index_sequence<Is...>) {
    ((W[Is] = (base + (int)Is >= 0 && base + (int)Is < N)
                  ? xb[(size_t)(base + (int)Is) * D_DIM]
                  : 0.0f),
     ...);
}

template <int Rr, size_t... Is>
__device__ __forceinline__ float dot_row(const float (&W)[WINW],
                                         const float* __restrict__ wrow,
                                         std::index_sequence<Is...>) {
    float acc[4] = {0.f, 0.f, 0.f, 0.f};
    ((acc[Is & 3] = fmaf(W[Rr + (int)Is], wrow[Is], acc[Is & 3])), ...);
    return (acc[0] + acc[1]) + (acc[2] + acc[3]);
}

template <size_t... Rs>
__device__ __forceinline__ void all_rows(const float (&W)[WINW],
                                         const float* __restrict__ smb,
                                         const float* __restrict__ szb,
                                         float* __restrict__ ob,
                                         int n0, int N, bool full,
                                         std::index_sequence<Rs...>) {
    (([&] {
         const int n = n0 + (int)Rs;
         if (full || n < N) {                            // wave-uniform
             const float* __restrict__ wrow = smb + (size_t)n * WID; // s_load
             const float s =
                 dot_row<(int)Rs>(W, wrow, std::make_index_sequence<WID>{});
             const float inv = __builtin_amdgcn_rcpf(fmaxf(szb[n], 1e-6f));
             ob[(size_t)n * D_DIM] = s * inv;
         }
     }()),
     ...);
}

__global__ __launch_bounds__(256, 4) void local_enc_kernel(
    const float* __restrict__ x, const float* __restrict__ sizev,
    const float* __restrict__ sm, float* __restrict__ out, int N) {
    const int d  = threadIdx.x;
    const int b  = blockIdx.y;
    const int n0 = blockIdx.x * RSTR;

    const size_t bN = (size_t)b * (size_t)N;
    const float* __restrict__ xb  = x   + bN * D_DIM + d;
    float*       __restrict__ ob  = out + bN * D_DIM + d;
    const float* __restrict__ smb = sm    + bN * WID;   // wave-uniform
    const float* __restrict__ szb = sizev + bN;         // wave-uniform

    const int  base     = n0 - CEN;                      // first window row
    const bool interior = (base >= 0) && (base + WINW <= N);
    const bool full     = (n0 + RSTR <= N);

    float W[WINW];
    if (interior)
        load_win(W, xb, base, std::make_index_sequence<WINW>{});
    else
        load_win_guard(W, xb, base, N, std::make_index_sequence<WINW>{});

    // Hard wall: no memory op crosses. All 65 loads in flight, one drain.
    asm volatile("" ::: "memory");

    all_rows(W, smb, szb, ob, n0, N, full, std::make_index_sequence<RSTR>{});
}

extern "C" void kernel_launch(void* const* d_in, const int* in_sizes, int n_in,
                              void* d_out, int out_size, void* d_ws, size_t ws_size,
                              hipStream_t stream) {
    const float* x  = (const float*)d_in[0];
    const float* sz = (const float*)d_in[1];
    const float* sm = (const float*)d_in[2];
    float* out = (float*)d_out;

    const int B = 8;
    const int N = 16384;

    dim3 grid((N + RSTR - 1) / RSTR, B, 1);   // 497 x 8 = 3976 blocks
    dim3 block(D_DIM, 1, 1);
    local_enc_kernel<<<grid, block, 0, stream>>>(x, sz, sm, out, N);
}

// Round 10
// 104.274 us; speedup vs baseline: 1.5270x; 1.0632x over previous
//
#include <hip/hip_runtime.h>
#include <utility>

#define D_DIM 256
#define WID   33
#define CEN   16
#define RSTR  33                   // rows per block — ONE strip, zero loops
#define WINW  (RSTR + WID - 1)     // 65-value x register window
#define WPAD  36                   // padded weight row (16B-aligned rows)
#define LW_N  (RSTR * WPAD)

// R9 post-mortem: asm fence defeated (VGPR stuck at 40). Real first-order
// stall: per-row weights are wave-uniform s_loads from L3 (~300-500cy) and
// SGPR budget only prefetches ~1.5 rows ahead -> ~33 serialized scalar-load
// latencies per strip (~10K cy) vs 2.2K cy of FMA => VALUBusy 24%.
// Fix: weights have 256-way reuse across d -> stage strip weights (+sizes)
// in LDS once (4.9KB, one barrier), rows read them via broadcast ds_read
// (~120cy, pipelined inside the straight-line 33-row body).

template <size_t... Is>
__device__ __forceinline__ void load_win(float (&W)[WINW],
                                         const float* __restrict__ xb,
                                         int base, std::index_sequence<Is...>) {
    ((W[Is] = xb[(size_t)(base + (int)Is) * D_DIM]), ...);
}

template <size_t... Is>
__device__ __forceinline__ void load_win_guard(float (&W)[WINW],
                                               const float* __restrict__ xb,
                                               int base, int N,
                                               std::index_sequence<Is...>) {
    ((W[Is] = (base + (int)Is >= 0 && base + (int)Is < N)
                  ? xb[(size_t)(base + (int)Is) * D_DIM]
                  : 0.0f),
     ...);
}

template <int Rr, size_t... Is>
__device__ __forceinline__ float dot_row(const float (&W)[WINW],
                                         const float (&lw)[LW_N],
                                         std::index_sequence<Is...>) {
    float acc[4] = {0.f, 0.f, 0.f, 0.f};
    ((acc[Is & 3] =
          fmaf(W[Rr + (int)Is], lw[Rr * WPAD + (int)Is], acc[Is & 3])),
     ...);
    return (acc[0] + acc[1]) + (acc[2] + acc[3]);
}

template <size_t... Rs>
__device__ __forceinline__ void all_rows(const float (&W)[WINW],
                                         const float (&lw)[LW_N],
                                         const float (&lsz)[RSTR],
                                         float* __restrict__ ob,
                                         int n0, int N, bool full,
                                         std::index_sequence<Rs...>) {
    (([&] {
         const int n = n0 + (int)Rs;
         if (full || n < N) {                            // wave-uniform
             const float s =
                 dot_row<(int)Rs>(W, lw, std::make_index_sequence<WID>{});
             const float inv =
                 __builtin_amdgcn_rcpf(fmaxf(lsz[(int)Rs], 1e-6f));
             ob[(size_t)n * D_DIM] = s * inv;
         }
     }()),
     ...);
}

__global__ __launch_bounds__(256, 4) void local_enc_kernel(
    const float* __restrict__ x, const float* __restrict__ sizev,
    const float* __restrict__ sm, float* __restrict__ out, int N) {
    __shared__ float lw[LW_N];     // 33 rows x 36 (padded) weights
    __shared__ float lsz[RSTR];

    const int d  = threadIdx.x;
    const int b  = blockIdx.y;
    const int n0 = blockIdx.x * RSTR;

    const size_t bN = (size_t)b * (size_t)N;
    const float* __restrict__ xb  = x   + bN * D_DIM + d;
    float*       __restrict__ ob  = out + bN * D_DIM + d;
    const float* __restrict__ smb = sm    + bN * WID;
    const float* __restrict__ szb = sizev + bN;

    // ---- stage weights + sizes into LDS (coalesced vector loads) ----
#pragma unroll
    for (int k = d; k < LW_N; k += D_DIM) {              // 5 iterations
        const int r = k / WPAD;
        const int o = k - r * WPAD;
        const int n = n0 + r;
        float v = 0.0f;
        if (o < WID && n < N) v = smb[(size_t)n * WID + o];
        lw[k] = v;
    }
    if (d < RSTR) {
        const int n = n0 + d;
        lsz[d] = (n < N) ? szb[n] : 1.0f;
    }
    __syncthreads();

    // ---- x register window (R8 structure: straight-line, no loops) ----
    const int  base     = n0 - CEN;
    const bool interior = (base >= 0) && (base + WINW <= N);
    const bool full     = (n0 + RSTR <= N);

    float W[WINW];
    if (interior)
        load_win(W, xb, base, std::make_index_sequence<WINW>{});
    else
        load_win_guard(W, xb, base, N, std::make_index_sequence<WINW>{});

    all_rows(W, lw, lsz, ob, n0, N, full, std::make_index_sequence<RSTR>{});
}

extern "C" void kernel_launch(void* const* d_in, const int* in_sizes, int n_in,
                              void* d_out, int out_size, void* d_ws, size_t ws_size,
                              hipStream_t stream) {
    const float* x  = (const float*)d_in[0];
    const float* sz = (const float*)d_in[1];
    const float* sm = (const float*)d_in[2];
    float* out = (float*)d_out;

    const int B = 8;
    const int N = 16384;

    dim3 grid((N + RSTR - 1) / RSTR, B, 1);   // 497 x 8 = 3976 blocks
    dim3 block(D_DIM, 1, 1);
    local_enc_kernel<<<grid, block, 0, stream>>>(x, sz, sm, out, N);
}